// Round 4
// baseline (1194.332 us; speedup 1.0000x reference)
//
#include <hip/hip_runtime.h>

#define NN 100000
#define NE 3200000
#define DI 128

// node-range bucketing: 128 nodes per bucket
#define RSH 7
#define RMASK 127
#define NB ((NN + RMASK) >> RSH)   // 782
#define NCHUNK 256
#define CHUNK ((NE + NCHUNK - 1) / NCHUNK)  // 12500

// ============ build pass 1: per-bucket histogram ============
__global__ __launch_bounds__(256) void hist_kernel(const int* __restrict__ dst,
                                                   int* __restrict__ bucket_cnt) {
    __shared__ int lh[NB];
    int tid = threadIdx.x;
    for (int i = tid; i < NB; i += 256) lh[i] = 0;
    __syncthreads();
    int base = blockIdx.x * CHUNK;
    int end = min(base + CHUNK, NE);
    for (int e = base + tid; e < end; e += 256)
        atomicAdd(&lh[dst[e] >> RSH], 1);
    __syncthreads();
    for (int i = tid; i < NB; i += 256) {
        int c = lh[i];
        if (c) atomicAdd(&bucket_cnt[i], c);
    }
}

// ============ build pass 2: exclusive scan (NB <= 1024) ============
__global__ __launch_bounds__(1024) void scan_kernel(const int* __restrict__ bucket_cnt,
                                                    int* __restrict__ bucket_ptr,
                                                    int* __restrict__ gcursor) {
    __shared__ int ls[1024];
    int tid = threadIdx.x;
    int v = (tid < NB) ? bucket_cnt[tid] : 0;
    ls[tid] = v;
    __syncthreads();
    for (int d = 1; d < 1024; d <<= 1) {
        int t = (tid >= d) ? ls[tid - d] : 0;
        __syncthreads();
        ls[tid] += t;
        __syncthreads();
    }
    if (tid < NB) {
        int excl = ls[tid] - v;
        bucket_ptr[tid] = excl;
        gcursor[tid] = excl;
    }
    if (tid == 1023) bucket_ptr[NB] = ls[1023];  // == NE
}

// ============ build pass 3: scatter records, bucket-contiguous ============
__global__ __launch_bounds__(256) void scatter_build_kernel(const int* __restrict__ src,
                                                            const int* __restrict__ dst,
                                                            int* __restrict__ gcursor,
                                                            unsigned* __restrict__ records) {
    __shared__ int lh[NB];
    __shared__ int lbase[NB];
    int tid = threadIdx.x;
    for (int i = tid; i < NB; i += 256) lh[i] = 0;
    __syncthreads();
    int base = blockIdx.x * CHUNK;
    int end = min(base + CHUNK, NE);
    for (int e = base + tid; e < end; e += 256)
        atomicAdd(&lh[dst[e] >> RSH], 1);
    __syncthreads();
    for (int i = tid; i < NB; i += 256) {
        int c = lh[i];
        lbase[i] = c ? atomicAdd(&gcursor[i], c) : 0;
        lh[i] = 0;  // reuse as local rank cursor
    }
    __syncthreads();
    for (int e = base + tid; e < end; e += 256) {
        int d = dst[e];
        int b = d >> RSH;
        int r = atomicAdd(&lh[b], 1);
        records[lbase[b] + r] = ((unsigned)src[e] << RSH) | (unsigned)(d & RMASK);
    }
}

// ============ dis from records (replaces 3.2M global-atomic deg count) ============
__global__ __launch_bounds__(256) void dis_kernel(const int* __restrict__ bucket_ptr,
                                                  const unsigned* __restrict__ records,
                                                  float* __restrict__ dis) {
    __shared__ int cnt[128];
    int tid = threadIdx.x, b = blockIdx.x;
    if (tid < 128) cnt[tid] = 0;
    __syncthreads();
    int beg = bucket_ptr[b], end = bucket_ptr[b + 1];
    for (int j = beg + tid; j < end; j += 256)
        atomicAdd(&cnt[records[j] & RMASK], 1);
    __syncthreads();
    if (tid < 128) {
        int n = (b << RSH) + tid;
        if (n < NN) dis[n] = rsqrtf((float)cnt[tid] + 1.0f);  // +1 self-loop
    }
}

// ============ dense GEMMs (epilogue: * dis[node]) ============
__global__ __launch_bounds__(256) void gemm1_kernel(const float* __restrict__ x,
                                                    const float* __restrict__ W,
                                                    const float* __restrict__ dis,
                                                    float* __restrict__ out) {
    __shared__ float Ws[DI][32];
    __shared__ float xs[8][DI];
    int tid = threadIdx.x;
    for (int i = tid; i < DI * 32; i += 256) Ws[i / 32][i % 32] = W[i];
    int node0 = blockIdx.x * 8;
    for (int i = tid; i < 8 * DI; i += 256) {
        int nl = i / DI, k = i % DI;
        int node = node0 + nl;
        xs[nl][k] = (node < NN) ? x[(size_t)node * DI + k] : 0.0f;
    }
    __syncthreads();
    int nl = tid / 32, col = tid % 32;
    int node = node0 + nl;
    if (node >= NN) return;
    float acc = 0.0f;
#pragma unroll 8
    for (int k = 0; k < DI; k++) acc += xs[nl][k] * Ws[k][col];
    out[(size_t)node * 32 + col] = dis[node] * acc;
}

__global__ __launch_bounds__(256) void gemm2_kernel(const float* __restrict__ h,
                                                    const float* __restrict__ W,
                                                    const float* __restrict__ dis,
                                                    float* __restrict__ out) {
    __shared__ float Ws[32][16];
    __shared__ float hs[16][32];
    int tid = threadIdx.x;
    for (int i = tid; i < 32 * 16; i += 256) Ws[i / 16][i % 16] = W[i];
    int node0 = blockIdx.x * 16;
    for (int i = tid; i < 16 * 32; i += 256) {
        int nl = i / 32, k = i % 32;
        int node = node0 + nl;
        hs[nl][k] = (node < NN) ? h[(size_t)node * 32 + k] : 0.0f;
    }
    __syncthreads();
    int nl = tid / 16, col = tid % 16;
    int node = node0 + nl;
    if (node >= NN) return;
    float acc = 0.0f;
#pragma unroll
    for (int k = 0; k < 32; k++) acc += hs[nl][k] * Ws[k][col];
    out[(size_t)node * 16 + col] = dis[node] * acc;
}

__global__ void gemm3_kernel(const float* __restrict__ h, const float* __restrict__ W,
                             const float* __restrict__ dis, float* __restrict__ out) {
    int i = blockIdx.x * blockDim.x + threadIdx.x;
    if (i >= NN) return;
    float acc = 0.0f;
#pragma unroll
    for (int k = 0; k < 16; k++) acc += h[(size_t)i * 16 + k] * W[k];
    out[i] = dis[i] * acc;
}

// ============ bucketed aggregation with LDS accumulators ============
// out[n*F+f] = (relu?) dis[n] * (sum_{s in N(n)} hwd[s*F+f] + hwd[n*F+f]) + b[f]
template <int F, bool RELU>
__global__ __launch_bounds__(512) void agg_kernel(const int* __restrict__ bucket_ptr,
                                                  const unsigned* __restrict__ records,
                                                  const float* __restrict__ hwd,
                                                  const float* __restrict__ dis,
                                                  const float* __restrict__ bias,
                                                  float* __restrict__ out) {
    __shared__ float acc[128 * F];
    int tid = threadIdx.x, b = blockIdx.x;
    for (int i = tid; i < 128 * F; i += 512) acc[i] = 0.0f;
    __syncthreads();
    int beg = bucket_ptr[b], end = bucket_ptr[b + 1];
    int f = tid % F;
    int slot = tid / F;
    constexpr int RP = 512 / F;
    for (int j = beg + slot; j < end; j += RP) {
        unsigned rec = records[j];
        int s = rec >> RSH;
        int dl = rec & RMASK;
        atomicAdd(&acc[dl * F + f], hwd[(size_t)s * F + f]);
    }
    __syncthreads();
    int n0 = b << RSH;
    for (int i = tid; i < 128 * F; i += 512) {
        int dl = i / F, ff = i % F;
        int node = n0 + dl;
        if (node < NN) {
            float v = acc[i] + hwd[(size_t)node * F + ff];  // self-loop term
            v = dis[node] * v + bias[ff];
            out[(size_t)node * F + ff] = RELU ? fmaxf(v, 0.0f) : v;
        }
    }
}

extern "C" void kernel_launch(void* const* d_in, const int* in_sizes, int n_in,
                              void* d_out, int out_size, void* d_ws, size_t ws_size,
                              hipStream_t stream) {
    const float* x  = (const float*)d_in[0];
    const int*   ei = (const int*)d_in[1];
    const int*   src = ei;        // edge_index[0]
    const int*   dst = ei + NE;   // edge_index[1]
    const float* W1 = (const float*)d_in[2];
    const float* b1 = (const float*)d_in[3];
    const float* W2 = (const float*)d_in[4];
    const float* b2 = (const float*)d_in[5];
    const float* W3 = (const float*)d_in[6];
    const float* b3 = (const float*)d_in[7];
    float* out = (float*)d_out;
    float* ws  = (float*)d_ws;

    // workspace layout (4B units):
    //   dis        [0, NN)
    //   bucket_cnt [NN, NN+NB)
    //   bucket_ptr [NN+NB, NN+2NB+1)
    //   gcursor    [NN+2NB+1, NN+3NB+1)
    //   records    [A, A+NE)          A = NN + 3NB + 64 (aligned headroom)
    //   hwd1 [B, B+32NN), h1 [B+32NN, B+64NN)   B = A + NE
    //   hwd2 = hwd1 (16NN), h2 = hwd1+16NN (16NN), hwd3 = h1 (NN)
    float*    dis        = ws;
    int*      bucket_cnt = (int*)(ws + (size_t)NN);
    int*      bucket_ptr = (int*)(ws + (size_t)NN + NB);
    int*      gcursor    = (int*)(ws + (size_t)NN + 2 * NB + 1);
    unsigned* records    = (unsigned*)(ws + (size_t)NN + 3 * NB + 64);
    float*    hwd1       = ws + (size_t)NN + 3 * NB + 64 + NE;
    float*    h1         = hwd1 + (size_t)32 * NN;
    float*    hwd2       = hwd1;                      // 16NN, reuses hwd1
    float*    h2         = hwd1 + (size_t)16 * NN;    // disjoint from hwd2
    float*    hwd3       = h1;                        // NN, h1 dead after gemm2

    // ---- build bucketed edge structure (shared by all 3 layers) ----
    hipMemsetAsync(bucket_cnt, 0, NB * sizeof(int), stream);
    hist_kernel<<<NCHUNK, 256, 0, stream>>>(dst, bucket_cnt);
    scan_kernel<<<1, 1024, 0, stream>>>(bucket_cnt, bucket_ptr, gcursor);
    scatter_build_kernel<<<NCHUNK, 256, 0, stream>>>(src, dst, gcursor, records);
    dis_kernel<<<NB, 256, 0, stream>>>(bucket_ptr, records, dis);

    // ---- layer 1 ----
    gemm1_kernel<<<(NN + 7) / 8, 256, 0, stream>>>(x, W1, dis, hwd1);
    agg_kernel<32, true><<<NB, 512, 0, stream>>>(bucket_ptr, records, hwd1, dis, b1, h1);
    // ---- layer 2 ----
    gemm2_kernel<<<(NN + 15) / 16, 256, 0, stream>>>(h1, W2, dis, hwd2);
    agg_kernel<16, true><<<NB, 512, 0, stream>>>(bucket_ptr, records, hwd2, dis, b2, h2);
    // ---- layer 3 ----
    gemm3_kernel<<<(NN + 255) / 256, 256, 0, stream>>>(h2, W3, dis, hwd3);
    agg_kernel<1, false><<<NB, 512, 0, stream>>>(bucket_ptr, records, hwd3, dis, b3, out);
}

// Round 5
// 274.507 us; speedup vs baseline: 4.3508x; 4.3508x over previous
//
#include <hip/hip_runtime.h>

#define NN 100000
#define NE 3200000
#define DI 128

// node-range bucketing: 128 nodes per bucket
#define RSH 7
#define RMASK 127
#define NB ((NN + RMASK) >> RSH)   // 782
#define NCHUNK 256
#define CHUNK ((NE + NCHUNK - 1) / NCHUNK)  // 12500

// ---- workspace layout (4-byte units) ----
// dis     [0, NN)
// bcnt    [NN, NN+NB)
// bptr    [100782, +NB+1)
// gcur    [101565, +NB)
// rowptr  [102400, +NN+1)
// srcs    [202752, +NE)
// hwd1    [202752+NE, +32NN)
// h1      [hwd1+32NN, +32NN)   -- 'records' aliases h1 (NE == 32NN), dead before agg writes h1
// h2 = hwd1+16NN, hwd3 = h1.  Total = 9,802,752 floats = 39.2 MB (< proven 39.6 MB)
#define OFF_BCNT   ((size_t)NN)
#define OFF_BPTR   ((size_t)100782)
#define OFF_GCUR   ((size_t)101565)
#define OFF_ROWPTR ((size_t)102400)
#define OFF_SRCS   ((size_t)202752)
#define OFF_HWD1   (OFF_SRCS + NE)

// ============ build 1: per-bucket histogram ============
__global__ __launch_bounds__(256) void hist_kernel(const int* __restrict__ dst,
                                                   int* __restrict__ bcnt) {
    __shared__ int lh[NB];
    int tid = threadIdx.x;
    for (int i = tid; i < NB; i += 256) lh[i] = 0;
    __syncthreads();
    int base = blockIdx.x * CHUNK;
    int end = min(base + CHUNK, NE);
    for (int e = base + tid; e < end; e += 256)
        atomicAdd(&lh[dst[e] >> RSH], 1);
    __syncthreads();
    for (int i = tid; i < NB; i += 256) {
        int c = lh[i];
        if (c) atomicAdd(&bcnt[i], c);
    }
}

// ============ build 2: exclusive scan over buckets ============
__global__ __launch_bounds__(1024) void scan_kernel(const int* __restrict__ bcnt,
                                                    int* __restrict__ bptr,
                                                    int* __restrict__ gcur) {
    __shared__ int ls[1024];
    int tid = threadIdx.x;
    int v = (tid < NB) ? bcnt[tid] : 0;
    ls[tid] = v;
    __syncthreads();
    for (int d = 1; d < 1024; d <<= 1) {
        int t = (tid >= d) ? ls[tid - d] : 0;
        __syncthreads();
        ls[tid] += t;
        __syncthreads();
    }
    if (tid < NB) {
        int excl = ls[tid] - v;
        bptr[tid] = excl;
        gcur[tid] = excl;
    }
    if (tid == 1023) bptr[NB] = ls[1023];  // == NE
}

// ============ build 3: scatter records bucket-contiguous ============
// record = (src << 7) | (dst & 127)
__global__ __launch_bounds__(256) void scatter_build_kernel(const int* __restrict__ src,
                                                            const int* __restrict__ dst,
                                                            int* __restrict__ gcur,
                                                            unsigned* __restrict__ records) {
    __shared__ int lh[NB];
    __shared__ int lbase[NB];
    int tid = threadIdx.x;
    for (int i = tid; i < NB; i += 256) lh[i] = 0;
    __syncthreads();
    int base = blockIdx.x * CHUNK;
    int end = min(base + CHUNK, NE);
    for (int e = base + tid; e < end; e += 256)
        atomicAdd(&lh[dst[e] >> RSH], 1);
    __syncthreads();
    for (int i = tid; i < NB; i += 256) {
        int c = lh[i];
        lbase[i] = c ? atomicAdd(&gcur[i], c) : 0;
        lh[i] = 0;  // reuse as local rank cursor
    }
    __syncthreads();
    for (int e = base + tid; e < end; e += 256) {
        int d = dst[e];
        int b = d >> RSH;
        int r = atomicAdd(&lh[b], 1);
        records[lbase[b] + r] = ((unsigned)src[e] << RSH) | (unsigned)(d & RMASK);
    }
}

// ============ build 4: per-bucket counting sort -> CSR + dis ============
__global__ __launch_bounds__(256) void bucket_csr_kernel(const int* __restrict__ bptr,
                                                         const unsigned* __restrict__ records,
                                                         int* __restrict__ rowptr,
                                                         int* __restrict__ srcs,
                                                         float* __restrict__ dis) {
    __shared__ int cnt[128];
    __shared__ int sc[128];
    __shared__ int cur[128];
    int tid = threadIdx.x, b = blockIdx.x;
    if (tid < 128) cnt[tid] = 0;
    __syncthreads();
    int beg = bptr[b], end = bptr[b + 1];
    for (int j = beg + tid; j < end; j += 256)
        atomicAdd(&cnt[records[j] & RMASK], 1);
    __syncthreads();
    if (tid < 128) sc[tid] = cnt[tid];
    __syncthreads();
    for (int d = 1; d < 128; d <<= 1) {
        int v = (tid < 128 && tid >= d) ? sc[tid - d] : 0;
        __syncthreads();
        if (tid < 128) sc[tid] += v;
        __syncthreads();
    }
    if (tid < 128) {
        int excl = sc[tid] - cnt[tid];
        cur[tid] = excl;
        int node = (b << RSH) + tid;
        if (node < NN) {
            rowptr[node] = beg + excl;
            dis[node] = rsqrtf((float)cnt[tid] + 1.0f);  // +1 self-loop
        }
    }
    if (b == 0 && tid == 0) rowptr[NN] = NE;
    __syncthreads();
    for (int j = beg + tid; j < end; j += 256) {
        unsigned rec = records[j];
        int pos = beg + atomicAdd(&cur[rec & RMASK], 1);
        srcs[pos] = (int)(rec >> RSH);
    }
}

// ============ dense GEMMs (epilogue: * dis[node]) ============
__global__ __launch_bounds__(256) void gemm1_kernel(const float* __restrict__ x,
                                                    const float* __restrict__ W,
                                                    const float* __restrict__ dis,
                                                    float* __restrict__ out) {
    __shared__ float Ws[DI][32];
    __shared__ float xs[8][DI];
    int tid = threadIdx.x;
    for (int i4 = tid; i4 < DI * 32 / 4; i4 += 256) {
        float4 w = reinterpret_cast<const float4*>(W)[i4];
        int base = i4 * 4;
        *reinterpret_cast<float4*>(&Ws[base / 32][base % 32]) = w;
    }
    int node0 = blockIdx.x * 8;
    for (int i4 = tid; i4 < 8 * DI / 4; i4 += 256) {
        int base = i4 * 4;
        int nl = base / DI, k = base % DI;
        int node = node0 + nl;
        float4 v = (node < NN) ? reinterpret_cast<const float4*>(x)[((size_t)node * DI + k) / 4]
                               : make_float4(0.f, 0.f, 0.f, 0.f);
        *reinterpret_cast<float4*>(&xs[nl][k]) = v;
    }
    __syncthreads();
    int nl = tid / 32, col = tid % 32;
    int node = node0 + nl;
    if (node >= NN) return;
    float acc = 0.0f;
#pragma unroll 8
    for (int k = 0; k < DI; k++) acc += xs[nl][k] * Ws[k][col];
    out[(size_t)node * 32 + col] = dis[node] * acc;
}

__global__ __launch_bounds__(256) void gemm2_kernel(const float* __restrict__ h,
                                                    const float* __restrict__ W,
                                                    const float* __restrict__ dis,
                                                    float* __restrict__ out) {
    __shared__ float Ws[32][16];
    __shared__ float hs[16][32];
    int tid = threadIdx.x;
    for (int i = tid; i < 32 * 16; i += 256) Ws[i / 16][i % 16] = W[i];
    int node0 = blockIdx.x * 16;
    for (int i4 = tid; i4 < 16 * 32 / 4; i4 += 256) {
        int base = i4 * 4;
        int nl = base / 32, k = base % 32;
        int node = node0 + nl;
        float4 v = (node < NN) ? reinterpret_cast<const float4*>(h)[((size_t)node * 32 + k) / 4]
                               : make_float4(0.f, 0.f, 0.f, 0.f);
        *reinterpret_cast<float4*>(&hs[nl][k]) = v;
    }
    __syncthreads();
    int nl = tid / 16, col = tid % 16;
    int node = node0 + nl;
    if (node >= NN) return;
    float acc = 0.0f;
#pragma unroll
    for (int k = 0; k < 32; k++) acc += hs[nl][k] * Ws[k][col];
    out[(size_t)node * 16 + col] = dis[node] * acc;
}

__global__ void gemm3_kernel(const float* __restrict__ h, const float* __restrict__ W,
                             const float* __restrict__ dis, float* __restrict__ out) {
    int i = blockIdx.x * blockDim.x + threadIdx.x;
    if (i >= NN) return;
    float acc = 0.0f;
#pragma unroll
    for (int k = 0; k < 16; k++) acc += h[(size_t)i * 16 + k] * W[k];
    out[i] = dis[i] * acc;
}

// ============ CSR aggregation, float4 lanes + 4-deep unroll ============
// out[n,:] = (relu?) dis[n] * (sum_{s in N(n)} hwd[s,:] + hwd[n,:]) + b
template <int F, int VL, bool RELU>  // VL lanes per node, each lane owns 4 floats
__global__ __launch_bounds__(256) void agg4_kernel(const int* __restrict__ rowptr,
                                                   const int* __restrict__ srcs,
                                                   const float* __restrict__ hwd,
                                                   const float* __restrict__ dis,
                                                   const float* __restrict__ bias,
                                                   float* __restrict__ out) {
    int gtid = blockIdx.x * 256 + threadIdx.x;
    int node = gtid / VL;
    int lane = gtid % VL;
    if (node >= NN) return;
    int c4 = lane * 4;
    int beg = rowptr[node], end = rowptr[node + 1];
    const float4* hv = reinterpret_cast<const float4*>(hwd);
    float4 s = hv[((size_t)node * F + c4) / 4];  // self-loop term
    float ax = s.x, ay = s.y, az = s.z, aw = s.w;
    int j = beg;
    for (; j + 4 <= end; j += 4) {
        int s0 = srcs[j], s1 = srcs[j + 1], s2 = srcs[j + 2], s3 = srcs[j + 3];
        float4 v0 = hv[((size_t)s0 * F + c4) / 4];
        float4 v1 = hv[((size_t)s1 * F + c4) / 4];
        float4 v2 = hv[((size_t)s2 * F + c4) / 4];
        float4 v3 = hv[((size_t)s3 * F + c4) / 4];
        ax += v0.x + v1.x + v2.x + v3.x;
        ay += v0.y + v1.y + v2.y + v3.y;
        az += v0.z + v1.z + v2.z + v3.z;
        aw += v0.w + v1.w + v2.w + v3.w;
    }
    for (; j < end; j++) {
        float4 v = hv[((size_t)srcs[j] * F + c4) / 4];
        ax += v.x; ay += v.y; az += v.z; aw += v.w;
    }
    float d = dis[node];
    float4 r;
    r.x = d * ax + bias[c4 + 0];
    r.y = d * ay + bias[c4 + 1];
    r.z = d * az + bias[c4 + 2];
    r.w = d * aw + bias[c4 + 3];
    if (RELU) {
        r.x = fmaxf(r.x, 0.f); r.y = fmaxf(r.y, 0.f);
        r.z = fmaxf(r.z, 0.f); r.w = fmaxf(r.w, 0.f);
    }
    reinterpret_cast<float4*>(out)[((size_t)node * F + c4) / 4] = r;
}

// F=1 scalar variant
__global__ __launch_bounds__(256) void agg1_kernel(const int* __restrict__ rowptr,
                                                   const int* __restrict__ srcs,
                                                   const float* __restrict__ hwd,
                                                   const float* __restrict__ dis,
                                                   const float* __restrict__ bias,
                                                   float* __restrict__ out) {
    int node = blockIdx.x * 256 + threadIdx.x;
    if (node >= NN) return;
    int beg = rowptr[node], end = rowptr[node + 1];
    float acc = hwd[node];
    int j = beg;
    for (; j + 4 <= end; j += 4) {
        float v0 = hwd[srcs[j]], v1 = hwd[srcs[j + 1]];
        float v2 = hwd[srcs[j + 2]], v3 = hwd[srcs[j + 3]];
        acc += v0 + v1 + v2 + v3;
    }
    for (; j < end; j++) acc += hwd[srcs[j]];
    out[node] = dis[node] * acc + bias[0];
}

extern "C" void kernel_launch(void* const* d_in, const int* in_sizes, int n_in,
                              void* d_out, int out_size, void* d_ws, size_t ws_size,
                              hipStream_t stream) {
    const float* x  = (const float*)d_in[0];
    const int*   ei = (const int*)d_in[1];
    const int*   src = ei;        // edge_index[0]
    const int*   dst = ei + NE;   // edge_index[1]
    const float* W1 = (const float*)d_in[2];
    const float* b1 = (const float*)d_in[3];
    const float* W2 = (const float*)d_in[4];
    const float* b2 = (const float*)d_in[5];
    const float* W3 = (const float*)d_in[6];
    const float* b3 = (const float*)d_in[7];
    float* out = (float*)d_out;
    float* ws  = (float*)d_ws;

    float*    dis     = ws;
    int*      bcnt    = (int*)(ws + OFF_BCNT);
    int*      bptr    = (int*)(ws + OFF_BPTR);
    int*      gcur    = (int*)(ws + OFF_GCUR);
    int*      rowptr  = (int*)(ws + OFF_ROWPTR);
    int*      srcs    = (int*)(ws + OFF_SRCS);
    float*    hwd1    = ws + OFF_HWD1;
    float*    h1      = hwd1 + (size_t)32 * NN;
    unsigned* records = (unsigned*)h1;               // NE == 32*NN, dead before agg writes h1
    float*    hwd2    = hwd1;                        // 16NN
    float*    h2      = hwd1 + (size_t)16 * NN;      // 16NN
    float*    hwd3    = h1;                          // NN (h1 dead after gemm2)

    // ---- build CSR (shared by all 3 layers) ----
    hipMemsetAsync(bcnt, 0, NB * sizeof(int), stream);
    hist_kernel<<<NCHUNK, 256, 0, stream>>>(dst, bcnt);
    scan_kernel<<<1, 1024, 0, stream>>>(bcnt, bptr, gcur);
    scatter_build_kernel<<<NCHUNK, 256, 0, stream>>>(src, dst, gcur, records);
    bucket_csr_kernel<<<NB, 256, 0, stream>>>(bptr, records, rowptr, srcs, dis);

    // ---- layer 1 ----
    gemm1_kernel<<<(NN + 7) / 8, 256, 0, stream>>>(x, W1, dis, hwd1);
    agg4_kernel<32, 8, true><<<((size_t)NN * 8 + 255) / 256, 256, 0, stream>>>(rowptr, srcs, hwd1, dis, b1, h1);
    // ---- layer 2 ----
    gemm2_kernel<<<(NN + 15) / 16, 256, 0, stream>>>(h1, W2, dis, hwd2);
    agg4_kernel<16, 4, true><<<((size_t)NN * 4 + 255) / 256, 256, 0, stream>>>(rowptr, srcs, hwd2, dis, b2, h2);
    // ---- layer 3 ----
    gemm3_kernel<<<(NN + 255) / 256, 256, 0, stream>>>(h2, W3, dis, hwd3);
    agg1_kernel<<<(NN + 255) / 256, 256, 0, stream>>>(rowptr, srcs, hwd3, dis, b3, out);
}